// Round 4
// baseline (531.651 us; speedup 1.0000x reference)
//
#include <hip/hip_runtime.h>
#include <hip/hip_bf16.h>

#define D_DIM 512
#define H_DIM 512
#define G_SEG 1024
#define BM    128

typedef __attribute__((ext_vector_type(8))) short bf16x8;
typedef __attribute__((ext_vector_type(4))) float f32x4;
typedef unsigned int u32;
typedef unsigned short u16;

// ---- workspace ----
#define WS_S   0         // G f32
#define WS_WB  8192      // 512 KB bf16 W in MFMA-fragment granule layout

// ---- LDS ----  As: 128 rows x 1024B (bf16 x 512, XOR-swizzled)
#define AS_BYTES  (128 * 1024)
#define BETA_OFF  AS_BYTES
#define EBS_OFF   (BETA_OFF + 4 * 128 * 4)
#define SIDX_OFF  (EBS_OFF + 128 * 4)
#define LDS_TOTAL (SIDX_OFF + 128 * 4)

static __device__ __forceinline__ u16 f2bf(float f) {
    __hip_bfloat16 h = __float2bfloat16(f);
    return *(u16*)&h;
}
static __device__ __forceinline__ float bf2f(u16 u) {
    return __uint_as_float(((u32)u) << 16);
}
static __device__ __forceinline__ float fast_tanh(float x) {
    float e = exp2f(x * 2.885390081777927f);   // e^(2x)
    return 1.0f - 2.0f * __builtin_amdgcn_rcpf(e + 1.0f);
}

// ---- W fp32 -> bf16 in granule layout: granule(k32, c, lhi) = W[c][k32*32 + lhi*8 .. +8]
__global__ __launch_bounds__(256)
void cvt_w(const float* __restrict__ W, u16* __restrict__ Wb) {
    int t   = blockIdx.x * 256 + threadIdx.x;   // 32768 granules
    int lhi = t & 3;
    int c   = (t >> 2) & 511;
    int k32 = t >> 11;
    const float* src = W + (size_t)c * 512 + k32 * 32 + lhi * 8;
    float4 f0 = *(const float4*)(src);
    float4 f1 = *(const float4*)(src + 4);
    u16 h[8];
    h[0]=f2bf(f0.x); h[1]=f2bf(f0.y); h[2]=f2bf(f0.z); h[3]=f2bf(f0.w);
    h[4]=f2bf(f1.x); h[5]=f2bf(f1.y); h[6]=f2bf(f1.z); h[7]=f2bf(f1.w);
    *(uint4*)(Wb + (size_t)t * 8) = *(uint4*)h;
}

// ---- fused: GEMM(128 x 512 x 512) + tanh*V reduce + exp + segment sums ----
__global__ __launch_bounds__(512, 2)
void fused(const float* __restrict__ E, const int* __restrict__ BI,
           const u16* __restrict__ Wb, const float* __restrict__ V,
           float* __restrict__ out, float* __restrict__ S)
{
    extern __shared__ char smem[];
    const int tid = threadIdx.x;
    const int nodeBase = blockIdx.x * BM;
    const int l   = tid & 63;
    const int w   = tid >> 6;
    const int wr  = w >> 2;       // 2 row groups (64 rows)
    const int wc  = w & 3;        // 4 col groups (128 cols)
    const int l15 = l & 15;
    const int lhi = l >> 4;

    const float* Eb = E + (size_t)nodeBase * 512;
    const int arow = tid >> 3;    // 0..63, second row = arow+64
    const int aj   = tid & 7;

    f32x4 acc[4][8];
#pragma unroll
    for (int m = 0; m < 4; ++m)
#pragma unroll
        for (int n = 0; n < 8; ++n) acc[m][n] = (f32x4){0.f, 0.f, 0.f, 0.f};

    // per-lane b-frag byte offset within a 32-k (32KB) W slab
    const int bOffBase = ((wc * 128 + l15) * 4 + lhi) * 16;

    float4 aload[4];
    {   // prologue E loads for ks=0
        const float* p0 = Eb + (size_t)arow * 512 + aj * 8;
        aload[0] = *(const float4*)p0;       aload[1] = *(const float4*)(p0 + 4);
        const float* p1 = p0 + 64 * 512;
        aload[2] = *(const float4*)p1;       aload[3] = *(const float4*)(p1 + 4);
    }

    bf16x8 bA[8], bB[8];
    {   // prologue b-frags for kk=0
        const char* Wsub = (const char*)Wb;
#pragma unroll
        for (int n = 0; n < 8; ++n)
            bA[n] = *(const bf16x8*)(Wsub + bOffBase + n * (16 * 4 * 16));
    }

    for (int ks = 0; ks < 8; ++ks) {
        // ---- stage A slab ks: cvt fp32->bf16, swizzled 16B writes
        {
            u16 h[8];
            h[0]=f2bf(aload[0].x); h[1]=f2bf(aload[0].y); h[2]=f2bf(aload[0].z); h[3]=f2bf(aload[0].w);
            h[4]=f2bf(aload[1].x); h[5]=f2bf(aload[1].y); h[6]=f2bf(aload[1].z); h[7]=f2bf(aload[1].w);
            int byte0 = arow * 1024 + ((ks * 128 + aj * 16) ^ ((arow & 7) << 4));
            *(uint4*)(smem + byte0) = *(uint4*)h;
            h[0]=f2bf(aload[2].x); h[1]=f2bf(aload[2].y); h[2]=f2bf(aload[2].z); h[3]=f2bf(aload[2].w);
            h[4]=f2bf(aload[3].x); h[5]=f2bf(aload[3].y); h[6]=f2bf(aload[3].z); h[7]=f2bf(aload[3].w);
            *(uint4*)(smem + byte0 + 64 * 1024) = *(uint4*)h;
        }
        // ---- prefetch next slab's E while this kstep computes
        if (ks < 7) {
            const float* p0 = Eb + (size_t)arow * 512 + (ks + 1) * 64 + aj * 8;
            aload[0] = *(const float4*)p0;   aload[1] = *(const float4*)(p0 + 4);
            const float* p1 = p0 + 64 * 512;
            aload[2] = *(const float4*)p1;   aload[3] = *(const float4*)(p1 + 4);
        }
        __syncthreads();

        // ---- ksub 0: prefetch b for kk=2ks+1, compute with bA
        {
            const char* Wnext = (const char*)Wb + ((size_t)(ks * 2 + 1) << 15);
#pragma unroll
            for (int n = 0; n < 8; ++n)
                bB[n] = *(const bf16x8*)(Wnext + bOffBase + n * (16 * 4 * 16));

            bf16x8 a[4];
            const int kbyte = ks * 128 + lhi * 16;
#pragma unroll
            for (int m = 0; m < 4; ++m) {
                int row = wr * 64 + m * 16 + l15;
                a[m] = *(const bf16x8*)(smem + row * 1024 + (kbyte ^ ((row & 7) << 4)));
            }
#pragma unroll
            for (int m = 0; m < 4; ++m)
#pragma unroll
                for (int n = 0; n < 8; ++n)
                    acc[m][n] = __builtin_amdgcn_mfma_f32_16x16x32_bf16(a[m], bA[n], acc[m][n], 0, 0, 0);
        }
        // ---- ksub 1: prefetch b for kk=2ks+2 (next ks), compute with bB
        {
            if (ks < 7) {
                const char* Wnext = (const char*)Wb + ((size_t)(ks * 2 + 2) << 15);
#pragma unroll
                for (int n = 0; n < 8; ++n)
                    bA[n] = *(const bf16x8*)(Wnext + bOffBase + n * (16 * 4 * 16));
            }
            bf16x8 a[4];
            const int kbyte = ks * 128 + 64 + lhi * 16;
#pragma unroll
            for (int m = 0; m < 4; ++m) {
                int row = wr * 64 + m * 16 + l15;
                a[m] = *(const bf16x8*)(smem + row * 1024 + (kbyte ^ ((row & 7) << 4)));
            }
#pragma unroll
            for (int m = 0; m < 4; ++m)
#pragma unroll
                for (int n = 0; n < 8; ++n)
                    acc[m][n] = __builtin_amdgcn_mfma_f32_16x16x32_bf16(a[m], bB[n], acc[m][n], 0, 0, 0);
        }
        // no trailing barrier: next iteration writes a DIFFERENT 16KB slab
    }

    // ---- epilogue: beta = sum_h V[h] * tanh(z[:,h])
    float Vv[8];
#pragma unroll
    for (int n = 0; n < 8; ++n)
        Vv[n] = V[wc * 128 + n * 16 + l15];

    float bsum[4][4];
#pragma unroll
    for (int m = 0; m < 4; ++m)
#pragma unroll
        for (int r = 0; r < 4; ++r) {
            float s = 0.f;
#pragma unroll
            for (int n = 0; n < 8; ++n)
                s += Vv[n] * fast_tanh(acc[m][n][r]);
            bsum[m][r] = s;
        }
#pragma unroll
    for (int off = 1; off <= 8; off <<= 1)
#pragma unroll
        for (int m = 0; m < 4; ++m)
#pragma unroll
            for (int r = 0; r < 4; ++r)
                bsum[m][r] += __shfl_xor(bsum[m][r], off, 64);

    float* betaP = (float*)(smem + BETA_OFF);
    if (l15 == 0) {
#pragma unroll
        for (int m = 0; m < 4; ++m)
#pragma unroll
            for (int r = 0; r < 4; ++r)
                betaP[wc * 128 + wr * 64 + m * 16 + lhi * 4 + r] = bsum[m][r];
    }
    __syncthreads();

    // ---- eb = exp(beta); S[g] += eb (wave-aggregated; rows sorted)
    float* ebs  = (float*)(smem + EBS_OFF);
    int*   sidx = (int*)(smem + SIDX_OFF);
    if (tid < 128) {
        float beta = betaP[tid] + betaP[128 + tid] + betaP[256 + tid] + betaP[384 + tid];
        float eb = expf(beta);
        ebs[tid] = eb;
        int g = BI[nodeBase + tid];
        sidx[tid] = g;
        int g0 = __shfl(g, 0, 64);
        if (__all(g == g0)) {
            float s = eb;
#pragma unroll
            for (int off = 1; off <= 32; off <<= 1)
                s += __shfl_xor(s, off, 64);
            if (l == 0) atomicAdd(&S[g], s);
        } else {
            atomicAdd(&S[g], eb);
        }
    }
    __syncthreads();

    // ---- weighted segment sum from LDS bf16 tile (vectorized):
    // thread t: cols [8*(t&63) .. +7], rows [16*(t>>6) .. +15]
    {
        const int c8    = tid & 63;
        const int rbase = (tid >> 6) * 16;
        const int cbyte = c8 * 16;
        float a[8];
#pragma unroll
        for (int j = 0; j < 8; ++j) a[j] = 0.f;
        int gcur = sidx[rbase];
        for (int rr = 0; rr < 16; ++rr) {
            int r = rbase + rr;
            int g = sidx[r];                     // wave-uniform
            if (g != gcur) {
                float* o = out + (size_t)gcur * 512 + c8 * 8;
#pragma unroll
                for (int j = 0; j < 8; ++j) atomicAdd(o + j, a[j]);
#pragma unroll
                for (int j = 0; j < 8; ++j) a[j] = 0.f;
                gcur = g;
            }
            float wgt = ebs[r];
            bf16x8 v = *(const bf16x8*)(smem + r * 1024 + (cbyte ^ ((r & 7) << 4)));
#pragma unroll
            for (int j = 0; j < 8; ++j)
                a[j] += wgt * bf2f((u16)v[j]);
        }
        float* o = out + (size_t)gcur * 512 + c8 * 8;
#pragma unroll
        for (int j = 0; j < 8; ++j) atomicAdd(o + j, a[j]);
    }
}

__global__ __launch_bounds__(256)
void finalize_kernel(float* __restrict__ out, const float* __restrict__ S) {
    int idx = blockIdx.x * 256 + threadIdx.x;
    float s = S[idx >> 9];
    float v = out[idx];
    out[idx] = (s != 0.f) ? v * __builtin_amdgcn_rcpf(s) : 0.f;
}

extern "C" void kernel_launch(void* const* d_in, const int* in_sizes, int n_in,
                              void* d_out, int out_size, void* d_ws, size_t ws_size,
                              hipStream_t stream) {
    const float* E  = (const float*)d_in[0];
    const int*   BI = (const int*)d_in[1];
    const float* W  = (const float*)d_in[2];
    const float* V  = (const float*)d_in[3];
    float* out = (float*)d_out;
    char*  ws  = (char*)d_ws;
    const int Ntot = in_sizes[0] / D_DIM;

    float* S  = (float*)(ws + WS_S);
    u16*   Wb = (u16*)(ws + WS_WB);

    hipMemsetAsync(S, 0, G_SEG * 4, stream);
    hipMemsetAsync(out, 0, (size_t)out_size * 4, stream);
    hipFuncSetAttribute((const void*)fused,
                        hipFuncAttributeMaxDynamicSharedMemorySize, LDS_TOTAL);

    cvt_w<<<128, 256, 0, stream>>>(W, Wb);
    fused<<<Ntot / BM, 512, LDS_TOTAL, stream>>>(E, BI, Wb, V, out, S);
    finalize_kernel<<<out_size / 256, 256, 0, stream>>>(out, S);
}

// Round 5
// 442.829 us; speedup vs baseline: 1.2006x; 1.2006x over previous
//
#include <hip/hip_runtime.h>
#include <hip/hip_bf16.h>

#define D_DIM 512
#define H_DIM 512
#define G_SEG 1024
#define BM    64

typedef __attribute__((ext_vector_type(8))) short bf16x8;
typedef __attribute__((ext_vector_type(4))) float f32x4;
typedef unsigned int u32;
typedef unsigned short u16;

// ---- workspace ----
#define WS_S   0         // G f32
#define WS_WB  8192      // 512 KB bf16 W in MFMA-fragment granule layout

// ---- LDS ----  As: 64 rows x 1024B (bf16 x 512, XOR-swizzled)
#define AS_BYTES  (BM * 1024)
#define BETA_OFF  AS_BYTES
#define EBS_OFF   (BETA_OFF + 4 * BM * 4)
#define SIDX_OFF  (EBS_OFF + BM * 4)
#define LDS_TOTAL (SIDX_OFF + BM * 4)

static __device__ __forceinline__ u16 f2bf(float f) {
    __hip_bfloat16 h = __float2bfloat16(f);
    return *(u16*)&h;
}
static __device__ __forceinline__ float bf2f(u16 u) {
    return __uint_as_float(((u32)u) << 16);
}
static __device__ __forceinline__ float fast_tanh(float x) {
    float e = exp2f(x * 2.885390081777927f);   // e^(2x)
    return 1.0f - 2.0f * __builtin_amdgcn_rcpf(e + 1.0f);
}

// ---- W fp32 -> bf16 in granule layout: granule(k32, c, lhi) = W[c][k32*32 + lhi*8 .. +8]
__global__ __launch_bounds__(256)
void cvt_w(const float* __restrict__ W, u16* __restrict__ Wb) {
    int t   = blockIdx.x * 256 + threadIdx.x;   // 32768 granules
    int lhi = t & 3;
    int c   = (t >> 2) & 511;
    int k32 = t >> 11;
    const float* src = W + (size_t)c * 512 + k32 * 32 + lhi * 8;
    float4 f0 = *(const float4*)(src);
    float4 f1 = *(const float4*)(src + 4);
    u16 h[8];
    h[0]=f2bf(f0.x); h[1]=f2bf(f0.y); h[2]=f2bf(f0.z); h[3]=f2bf(f0.w);
    h[4]=f2bf(f1.x); h[5]=f2bf(f1.y); h[6]=f2bf(f1.z); h[7]=f2bf(f1.w);
    *(uint4*)(Wb + (size_t)t * 8) = *(uint4*)h;
}

// ---- fused: GEMM(64 x 512 x 512) + tanh*V reduce + exp + segment sums ----
__global__ __launch_bounds__(512, 4)
void fused(const float* __restrict__ E, const int* __restrict__ BI,
           const u16* __restrict__ Wb, const float* __restrict__ V,
           float* __restrict__ out, float* __restrict__ S)
{
    extern __shared__ char smem[];
    const int tid = threadIdx.x;
    const int nodeBase = blockIdx.x * BM;
    const int l   = tid & 63;
    const int w   = tid >> 6;
    const int wr  = w >> 2;       // 2 row groups (32 rows)
    const int wc  = w & 3;        // 4 col groups (128 cols)
    const int l15 = l & 15;
    const int lhi = l >> 4;

    const float* Eb = E + (size_t)nodeBase * 512;
    const int arow = tid >> 3;    // 0..63
    const int aj   = tid & 7;

    f32x4 acc[2][8];
#pragma unroll
    for (int m = 0; m < 2; ++m)
#pragma unroll
        for (int n = 0; n < 8; ++n) acc[m][n] = (f32x4){0.f, 0.f, 0.f, 0.f};

    // per-lane b-frag byte offset within a 32-k (32KB) W slab
    const int bOffBase = ((wc * 128 + l15) * 4 + lhi) * 16;

    float4 aload[2];
    {   // prologue E loads for ks=0
        const float* p0 = Eb + (size_t)arow * 512 + aj * 8;
        aload[0] = *(const float4*)p0;
        aload[1] = *(const float4*)(p0 + 4);
    }

    bf16x8 bA[8], bB[8];
    {   // prologue b-frags for kk=0
#pragma unroll
        for (int n = 0; n < 8; ++n)
            bA[n] = *(const bf16x8*)((const char*)Wb + bOffBase + n * (16 * 4 * 16));
    }

    for (int ks = 0; ks < 8; ++ks) {
        // ---- stage A slab ks: cvt fp32->bf16, one swizzled 16B write per thread
        {
            u16 h[8];
            h[0]=f2bf(aload[0].x); h[1]=f2bf(aload[0].y); h[2]=f2bf(aload[0].z); h[3]=f2bf(aload[0].w);
            h[4]=f2bf(aload[1].x); h[5]=f2bf(aload[1].y); h[6]=f2bf(aload[1].z); h[7]=f2bf(aload[1].w);
            int byte0 = arow * 1024 + ((ks * 128 + aj * 16) ^ ((arow & 7) << 4));
            *(uint4*)(smem + byte0) = *(uint4*)h;
        }
        // ---- prefetch next slab's E while this kstep computes
        if (ks < 7) {
            const float* p0 = Eb + (size_t)arow * 512 + (ks + 1) * 64 + aj * 8;
            aload[0] = *(const float4*)p0;
            aload[1] = *(const float4*)(p0 + 4);
        }
        __syncthreads();

        // ---- ksub 0: prefetch b for kk=2ks+1, compute with bA
        {
            const char* Wnext = (const char*)Wb + ((size_t)(ks * 2 + 1) << 15);
#pragma unroll
            for (int n = 0; n < 8; ++n)
                bB[n] = *(const bf16x8*)(Wnext + bOffBase + n * (16 * 4 * 16));

            bf16x8 a[2];
            const int kbyte = ks * 128 + lhi * 16;
#pragma unroll
            for (int m = 0; m < 2; ++m) {
                int row = wr * 32 + m * 16 + l15;
                a[m] = *(const bf16x8*)(smem + row * 1024 + (kbyte ^ ((row & 7) << 4)));
            }
#pragma unroll
            for (int m = 0; m < 2; ++m)
#pragma unroll
                for (int n = 0; n < 8; ++n)
                    acc[m][n] = __builtin_amdgcn_mfma_f32_16x16x32_bf16(a[m], bA[n], acc[m][n], 0, 0, 0);
        }
        // ---- ksub 1: prefetch b for next ks, compute with bB
        {
            if (ks < 7) {
                const char* Wnext = (const char*)Wb + ((size_t)(ks * 2 + 2) << 15);
#pragma unroll
                for (int n = 0; n < 8; ++n)
                    bA[n] = *(const bf16x8*)(Wnext + bOffBase + n * (16 * 4 * 16));
            }
            bf16x8 a[2];
            const int kbyte = ks * 128 + 64 + lhi * 16;
#pragma unroll
            for (int m = 0; m < 2; ++m) {
                int row = wr * 32 + m * 16 + l15;
                a[m] = *(const bf16x8*)(smem + row * 1024 + (kbyte ^ ((row & 7) << 4)));
            }
#pragma unroll
            for (int m = 0; m < 2; ++m)
#pragma unroll
                for (int n = 0; n < 8; ++n)
                    acc[m][n] = __builtin_amdgcn_mfma_f32_16x16x32_bf16(a[m], bB[n], acc[m][n], 0, 0, 0);
        }
        // no trailing barrier: next iteration writes a DIFFERENT 8KB slab
    }

    // ---- epilogue: beta = sum_h V[h] * tanh(z[:,h])
    float Vv[8];
#pragma unroll
    for (int n = 0; n < 8; ++n)
        Vv[n] = V[wc * 128 + n * 16 + l15];

    float bsum[2][4];
#pragma unroll
    for (int m = 0; m < 2; ++m)
#pragma unroll
        for (int r = 0; r < 4; ++r) {
            float s = 0.f;
#pragma unroll
            for (int n = 0; n < 8; ++n)
                s += Vv[n] * fast_tanh(acc[m][n][r]);
            bsum[m][r] = s;
        }
#pragma unroll
    for (int off = 1; off <= 8; off <<= 1)
#pragma unroll
        for (int m = 0; m < 2; ++m)
#pragma unroll
            for (int r = 0; r < 4; ++r)
                bsum[m][r] += __shfl_xor(bsum[m][r], off, 64);

    float* betaP = (float*)(smem + BETA_OFF);
    if (l15 == 0) {
#pragma unroll
        for (int m = 0; m < 2; ++m)
#pragma unroll
            for (int r = 0; r < 4; ++r)
                betaP[wc * BM + wr * 32 + m * 16 + lhi * 4 + r] = bsum[m][r];
    }
    __syncthreads();

    // ---- eb = exp(beta); S[g] += eb (wave-aggregated; rows sorted)
    float* ebs  = (float*)(smem + EBS_OFF);
    int*   sidx = (int*)(smem + SIDX_OFF);
    if (tid < BM) {
        float beta = betaP[tid] + betaP[BM + tid] + betaP[2 * BM + tid] + betaP[3 * BM + tid];
        float eb = expf(beta);
        ebs[tid] = eb;
        int g = BI[nodeBase + tid];
        sidx[tid] = g;
        int g0 = __shfl(g, 0, 64);
        if (__all(g == g0)) {
            float s = eb;
#pragma unroll
            for (int off = 1; off <= 32; off <<= 1)
                s += __shfl_xor(s, off, 64);
            if (l == 0) atomicAdd(&S[g], s);
        } else {
            atomicAdd(&S[g], eb);
        }
    }
    __syncthreads();

    // ---- weighted segment sum: thread t = column t over all 64 rows.
    // Lane-contiguous atomics coalesce into full lines (round-4 lesson).
    {
        const int c = tid;     // 512 cols
        float a = 0.f;
        int gcur = sidx[0];
        for (int r = 0; r < BM; ++r) {
            int g = sidx[r];                     // wave-uniform
            if (g != gcur) {
                atomicAdd(&out[(size_t)gcur * 512 + c], a);
                a = 0.f; gcur = g;
            }
            u16 v = *(const u16*)(smem + r * 1024 + ((2 * c) ^ ((r & 7) << 4)));
            a += ebs[r] * bf2f(v);
        }
        atomicAdd(&out[(size_t)gcur * 512 + c], a);
    }
}

__global__ __launch_bounds__(256)
void finalize_kernel(float* __restrict__ out, const float* __restrict__ S) {
    int idx = blockIdx.x * 256 + threadIdx.x;
    float s = S[idx >> 9];
    float v = out[idx];
    out[idx] = (s != 0.f) ? v * __builtin_amdgcn_rcpf(s) : 0.f;
}

extern "C" void kernel_launch(void* const* d_in, const int* in_sizes, int n_in,
                              void* d_out, int out_size, void* d_ws, size_t ws_size,
                              hipStream_t stream) {
    const float* E  = (const float*)d_in[0];
    const int*   BI = (const int*)d_in[1];
    const float* W  = (const float*)d_in[2];
    const float* V  = (const float*)d_in[3];
    float* out = (float*)d_out;
    char*  ws  = (char*)d_ws;
    const int Ntot = in_sizes[0] / D_DIM;

    float* S  = (float*)(ws + WS_S);
    u16*   Wb = (u16*)(ws + WS_WB);

    hipMemsetAsync(S, 0, G_SEG * 4, stream);
    hipMemsetAsync(out, 0, (size_t)out_size * 4, stream);
    hipFuncSetAttribute((const void*)fused,
                        hipFuncAttributeMaxDynamicSharedMemorySize, LDS_TOTAL);

    cvt_w<<<128, 256, 0, stream>>>(W, Wb);
    fused<<<Ntot / BM, 512, LDS_TOTAL, stream>>>(E, BI, Wb, V, out, S);
    finalize_kernel<<<out_size / 256, 256, 0, stream>>>(out, S);
}

// Round 6
// 333.353 us; speedup vs baseline: 1.5949x; 1.3284x over previous
//
#include <hip/hip_runtime.h>
#include <hip/hip_bf16.h>

#define D_DIM 512
#define H_DIM 512
#define G_SEG 1024
#define BM    64

typedef __attribute__((ext_vector_type(8))) short bf16x8;
typedef __attribute__((ext_vector_type(4))) float f32x4;
typedef unsigned int u32;
typedef unsigned short u16;

// ---- workspace ----
#define WS_S   0         // G f32
#define WS_WB  8192      // 512 KB bf16 W in MFMA-fragment granule layout

// ---- LDS ----  As: 64 rows x 1024B (bf16 x 512, XOR-swizzled)
#define AS_BYTES  (BM * 1024)
#define BETA_OFF  AS_BYTES
#define EBS_OFF   (BETA_OFF + 8 * BM * 4)
#define SIDX_OFF  (EBS_OFF + BM * 4)
#define LDS_TOTAL (SIDX_OFF + BM * 4)

static __device__ __forceinline__ u16 f2bf(float f) {
    __hip_bfloat16 h = __float2bfloat16(f);
    return *(u16*)&h;
}
static __device__ __forceinline__ float bf2f(u16 u) {
    return __uint_as_float(((u32)u) << 16);
}
static __device__ __forceinline__ float fast_tanh(float x) {
    float e = exp2f(x * 2.885390081777927f);   // e^(2x)
    return 1.0f - 2.0f * __builtin_amdgcn_rcpf(e + 1.0f);
}

// ---- W fp32 -> bf16 in granule layout: granule(k32, c, lhi) = W[c][k32*32 + lhi*8 .. +8]
__global__ __launch_bounds__(256)
void cvt_w(const float* __restrict__ W, u16* __restrict__ Wb) {
    int t   = blockIdx.x * 256 + threadIdx.x;   // 32768 granules
    int lhi = t & 3;
    int c   = (t >> 2) & 511;
    int k32 = t >> 11;
    const float* src = W + (size_t)c * 512 + k32 * 32 + lhi * 8;
    float4 f0 = *(const float4*)(src);
    float4 f1 = *(const float4*)(src + 4);
    u16 h[8];
    h[0]=f2bf(f0.x); h[1]=f2bf(f0.y); h[2]=f2bf(f0.z); h[3]=f2bf(f0.w);
    h[4]=f2bf(f1.x); h[5]=f2bf(f1.y); h[6]=f2bf(f1.z); h[7]=f2bf(f1.w);
    *(uint4*)(Wb + (size_t)t * 8) = *(uint4*)h;
}

// ---- fused: GEMM(64 x 512 x 512) + tanh*V reduce + exp + segment sums ----
// 8 waves = 8 col-groups of 64; each wave: 64 rows x 64 cols -> acc[4][4]
__global__ __launch_bounds__(512, 4)
void fused(const float* __restrict__ E, const int* __restrict__ BI,
           const u16* __restrict__ Wb, const float* __restrict__ V,
           float* __restrict__ out, float* __restrict__ S)
{
    extern __shared__ char smem[];
    const int tid = threadIdx.x;
    const int nodeBase = blockIdx.x * BM;
    const int l   = tid & 63;
    const int w   = tid >> 6;     // col group: cols [w*64, w*64+64)
    const int l15 = l & 15;
    const int lhi = l >> 4;

    const float* Eb = E + (size_t)nodeBase * 512;
    const int arow = tid >> 3;    // 0..63
    const int aj   = tid & 7;

    f32x4 acc[4][4];
#pragma unroll
    for (int m = 0; m < 4; ++m)
#pragma unroll
        for (int n = 0; n < 4; ++n) acc[m][n] = (f32x4){0.f, 0.f, 0.f, 0.f};

    // per-lane b-frag byte offset within a 32-k (32KB) W slab; stride per n = 1024B
    const int bOffBase = ((w * 64 + l15) * 4 + lhi) * 16;

    float4 aload[2];
    {   // prologue E loads for ks=0
        const float* p0 = Eb + (size_t)arow * 512 + aj * 8;
        aload[0] = *(const float4*)p0;
        aload[1] = *(const float4*)(p0 + 4);
    }

    for (int ks = 0; ks < 8; ++ks) {
        // ---- stage A slab ks: cvt fp32->bf16, one swizzled 16B write per thread
        {
            u16 h[8];
            h[0]=f2bf(aload[0].x); h[1]=f2bf(aload[0].y); h[2]=f2bf(aload[0].z); h[3]=f2bf(aload[0].w);
            h[4]=f2bf(aload[1].x); h[5]=f2bf(aload[1].y); h[6]=f2bf(aload[1].z); h[7]=f2bf(aload[1].w);
            int byte0 = arow * 1024 + ((ks * 128 + aj * 16) ^ ((arow & 7) << 4));
            *(uint4*)(smem + byte0) = *(uint4*)h;
        }
        // ---- prefetch next slab's E while this kstep computes
        if (ks < 7) {
            const float* p0 = Eb + (size_t)arow * 512 + (ks + 1) * 64 + aj * 8;
            aload[0] = *(const float4*)p0;
            aload[1] = *(const float4*)(p0 + 4);
        }
        __syncthreads();

        // ---- compute: 2 ksubs x 16 MFMA; b from L2-resident Wb, a from LDS.
        // unroll 1: keeps only one b[4] set live (register budget 128, no spill)
#pragma unroll 1
        for (int ksub = 0; ksub < 2; ++ksub) {
            const char* Wsub = (const char*)Wb + ((size_t)(ks * 2 + ksub) << 15);
            bf16x8 b[4];
#pragma unroll
            for (int n = 0; n < 4; ++n)
                b[n] = *(const bf16x8*)(Wsub + bOffBase + n * 1024);
            bf16x8 a[4];
            const int kbyte = ks * 128 + ksub * 64 + lhi * 16;
#pragma unroll
            for (int m = 0; m < 4; ++m) {
                int row = m * 16 + l15;
                a[m] = *(const bf16x8*)(smem + row * 1024 + (kbyte ^ ((row & 7) << 4)));
            }
#pragma unroll
            for (int m = 0; m < 4; ++m)
#pragma unroll
                for (int n = 0; n < 4; ++n)
                    acc[m][n] = __builtin_amdgcn_mfma_f32_16x16x32_bf16(a[m], b[n], acc[m][n], 0, 0, 0);
        }
        // no trailing barrier: next iteration writes a DIFFERENT 8KB slab
    }

    // ---- epilogue: beta-partial[row] = sum_{cols of this wave} V[c] * tanh(z[row][c])
    float Vv[4];
#pragma unroll
    for (int n = 0; n < 4; ++n)
        Vv[n] = V[w * 64 + n * 16 + l15];

    float bsum[4][4];
#pragma unroll
    for (int m = 0; m < 4; ++m)
#pragma unroll
        for (int r = 0; r < 4; ++r) {
            float s = 0.f;
#pragma unroll
            for (int n = 0; n < 4; ++n)
                s += Vv[n] * fast_tanh(acc[m][n][r]);
            bsum[m][r] = s;
        }
#pragma unroll
    for (int off = 1; off <= 8; off <<= 1)
#pragma unroll
        for (int m = 0; m < 4; ++m)
#pragma unroll
            for (int r = 0; r < 4; ++r)
                bsum[m][r] += __shfl_xor(bsum[m][r], off, 64);

    float* betaP = (float*)(smem + BETA_OFF);   // [8 col-groups][64 rows]
    if (l15 == 0) {
#pragma unroll
        for (int m = 0; m < 4; ++m)
#pragma unroll
            for (int r = 0; r < 4; ++r)
                betaP[w * BM + m * 16 + lhi * 4 + r] = bsum[m][r];
    }
    __syncthreads();

    // ---- eb = exp(beta); S[g] += eb (wave-aggregated; rows sorted)
    float* ebs  = (float*)(smem + EBS_OFF);
    int*   sidx = (int*)(smem + SIDX_OFF);
    if (tid < BM) {
        float beta = 0.f;
#pragma unroll
        for (int j = 0; j < 8; ++j)
            beta += betaP[j * BM + tid];
        float eb = expf(beta);
        ebs[tid] = eb;
        int g = BI[nodeBase + tid];
        sidx[tid] = g;
        int g0 = __shfl(g, 0, 64);
        if (__all(g == g0)) {
            float s = eb;
#pragma unroll
            for (int off = 1; off <= 32; off <<= 1)
                s += __shfl_xor(s, off, 64);
            if (l == 0) atomicAdd(&S[g], s);
        } else {
            atomicAdd(&S[g], eb);
        }
    }
    __syncthreads();

    // ---- weighted segment sum: thread t = column t over all 64 rows.
    // Lane-contiguous atomics coalesce into full lines (round-4 lesson).
    {
        const int c = tid;     // 512 cols
        float a = 0.f;
        int gcur = sidx[0];
        for (int r = 0; r < BM; ++r) {
            int g = sidx[r];                     // wave-uniform
            if (g != gcur) {
                atomicAdd(&out[(size_t)gcur * 512 + c], a);
                a = 0.f; gcur = g;
            }
            u16 v = *(const u16*)(smem + r * 1024 + ((2 * c) ^ ((r & 7) << 4)));
            a += ebs[r] * bf2f(v);
        }
        atomicAdd(&out[(size_t)gcur * 512 + c], a);
    }
}

__global__ __launch_bounds__(256)
void finalize_kernel(float* __restrict__ out, const float* __restrict__ S) {
    int idx = blockIdx.x * 256 + threadIdx.x;
    float s = S[idx >> 9];
    float v = out[idx];
    out[idx] = (s != 0.f) ? v * __builtin_amdgcn_rcpf(s) : 0.f;
}

extern "C" void kernel_launch(void* const* d_in, const int* in_sizes, int n_in,
                              void* d_out, int out_size, void* d_ws, size_t ws_size,
                              hipStream_t stream) {
    const float* E  = (const float*)d_in[0];
    const int*   BI = (const int*)d_in[1];
    const float* W  = (const float*)d_in[2];
    const float* V  = (const float*)d_in[3];
    float* out = (float*)d_out;
    char*  ws  = (char*)d_ws;
    const int Ntot = in_sizes[0] / D_DIM;

    float* S  = (float*)(ws + WS_S);
    u16*   Wb = (u16*)(ws + WS_WB);

    hipMemsetAsync(S, 0, G_SEG * 4, stream);
    hipMemsetAsync(out, 0, (size_t)out_size * 4, stream);
    hipFuncSetAttribute((const void*)fused,
                        hipFuncAttributeMaxDynamicSharedMemorySize, LDS_TOTAL);

    cvt_w<<<128, 256, 0, stream>>>(W, Wb);
    fused<<<Ntot / BM, 512, LDS_TOTAL, stream>>>(E, BI, Wb, V, out, S);
    finalize_kernel<<<out_size / 256, 256, 0, stream>>>(out, S);
}